// Round 19
// baseline (231.225 us; speedup 1.0000x reference)
//
#include <hip/hip_runtime.h>
#include <cmath>

#define SEQ 2048
#define DM 512
#define DFF 2048
#define NH 8
#define DKH 64
#define NROWS 8192  // B*S = 4*2048

typedef __attribute__((ext_vector_type(8))) short bf16x8;
typedef __attribute__((ext_vector_type(16))) float f32x16;

__device__ __forceinline__ ushort f2bf(float f) {
    uint u = __float_as_uint(f);
    u += 0x7fff + ((u >> 16) & 1);
    return (ushort)(u >> 16);
}
__device__ __forceinline__ float bf2f(ushort h) {
    return __uint_as_float(((uint)h) << 16);
}
__device__ __forceinline__ uint cvtpk_bf16(float a, float b) {
    uint r;
    asm("v_cvt_pk_bf16_f32 %0, %1, %2" : "=v"(r) : "v"(a), "v"(b));
    return r;
}
// async global->LDS, 16B per lane. LDS dest = base + lane*16 (linear).
__device__ __forceinline__ void gl_lds16(const void* g, void* l) {
    __builtin_amdgcn_global_load_lds(
        (const __attribute__((address_space(1))) void*)g,
        (__attribute__((address_space(3))) void*)l, 16, 0, 0);
}
// 128B-row LDS swizzle (attn): byte ^= (row&7)<<4
__device__ __forceinline__ void* swz(char* base, int row, int col) {
    int byte = (row << 7) + (col << 1);
    byte ^= (row & 7) << 4;
    return base + byte;
}
// gemm LDS swizzle: byte ^= ((row>>2)&7)<<4
__device__ __forceinline__ void* swzg(char* base, int row, int k) {
    int byte = (row << 7) + (k << 1);
    byte ^= ((row >> 2) & 7) << 4;
    return base + byte;
}
// 256B-row LDS swizzle (qkv V transpose tile): byte ^= (row&7)<<4
__device__ __forceinline__ void* swzv(char* base, int row, int col) {
    int byte = (row << 8) + (col << 1);
    byte ^= (row & 7) << 4;
    return base + byte;
}

// ---------------------------------------------------------------------------
// LayerNorm core (one row per wave)
// ---------------------------------------------------------------------------
template<bool SPLIT>
__device__ __forceinline__ void ln_row(const float* __restrict__ x,
        const float* __restrict__ g, const float* __restrict__ b,
        ushort* __restrict__ oh, ushort* __restrict__ ol, int row, int t) {
    const float* xr = x + (size_t)row * DM + t * 8;
    float v[8];
    *(float4*)&v[0] = *(const float4*)(xr);
    *(float4*)&v[4] = *(const float4*)(xr + 4);
    float s = 0.f;
    #pragma unroll
    for (int j = 0; j < 8; ++j) s += v[j];
    #pragma unroll
    for (int m = 32; m > 0; m >>= 1) s += __shfl_xor(s, m);
    float mean = s * (1.0f / DM);
    float ss = 0.f;
    #pragma unroll
    for (int j = 0; j < 8; ++j) { float d = v[j] - mean; ss += d * d; }
    #pragma unroll
    for (int m = 32; m > 0; m >>= 1) ss += __shfl_xor(ss, m);
    float inv = 1.0f / (sqrtf(ss * (1.0f / (DM - 1))) + 1e-6f);
    float gv[8], bv[8];
    *(float4*)&gv[0] = *(const float4*)(g + t * 8);
    *(float4*)&gv[4] = *(const float4*)(g + t * 8 + 4);
    *(float4*)&bv[0] = *(const float4*)(b + t * 8);
    *(float4*)&bv[4] = *(const float4*)(b + t * 8 + 4);
    union { ushort us[8]; float4 f4; } ph, pl;
    #pragma unroll
    for (int j = 0; j < 8; ++j) {
        float o = gv[j] * (v[j] - mean) * inv + bv[j];
        ushort hb = f2bf(o);
        ph.us[j] = hb;
        if (SPLIT) pl.us[j] = f2bf(o - bf2f(hb));
    }
    *(float4*)(oh + (size_t)row * DM + t * 8) = ph.f4;
    if (SPLIT) *(float4*)(ol + (size_t)row * DM + t * 8) = pl.f4;
}

template<bool SPLIT>
__global__ __launch_bounds__(256) void ln_kernel(const float* __restrict__ x,
        const float* __restrict__ g, const float* __restrict__ b,
        ushort* __restrict__ oh, ushort* __restrict__ ol) {
    ln_row<SPLIT>(x, g, b, oh, ol, blockIdx.x * 4 + (threadIdx.x >> 6),
                  threadIdx.x & 63);
}

// ---------------------------------------------------------------------------
// Merged prep: 6 weight transposes + mask bias/flags + LN1, ONE launch.
// ---------------------------------------------------------------------------
__global__ __launch_bounds__(256) void prep(
        const float* __restrict__ wq, const float* __restrict__ wk,
        const float* __restrict__ wv, const float* __restrict__ wo,
        const float* __restrict__ w1, const float* __restrict__ w2,
        const int* __restrict__ mask, const float* __restrict__ x,
        const float* __restrict__ g1, const float* __restrict__ be1,
        ushort* __restrict__ qh, ushort* __restrict__ ql,
        ushort* __restrict__ kh, ushort* __restrict__ vh,
        ushort* __restrict__ oh,
        ushort* __restrict__ w1t, ushort* __restrict__ w2t,
        ushort* __restrict__ mb, unsigned char* __restrict__ mflag,
        ushort* __restrict__ xn_h, ushort* __restrict__ xn_l) {
    __shared__ float tile[64][65];
    int id = blockIdx.x;
    int t = threadIdx.x;
    if (id < 768) {
        const float* W;
        ushort* Th;
        ushort* Tl = nullptr;
        int K, N, k0, n0;
        bool split = false;
        if (id < 256) {
            int z = id >> 6, r = id & 63;
            W = (z == 0) ? wq : (z == 1) ? wk : (z == 2) ? wv : wo;
            Th = (z == 0) ? qh : (z == 1) ? kh : (z == 2) ? vh : oh;
            Tl = (z == 0) ? ql : nullptr;
            split = (z == 0);
            K = DM; N = DM;
            k0 = (r >> 3) * 64; n0 = (r & 7) * 64;
        } else if (id < 512) {
            int r = id - 256;
            W = w1; Th = w1t; K = DM; N = DFF;
            k0 = (r & 7) * 64; n0 = (r >> 3) * 64;
        } else {
            int r = id - 512;
            W = w2; Th = w2t; K = DFF; N = DM;
            k0 = (r & 31) * 64; n0 = (r >> 5) * 64;
        }
        {
            int kr = t >> 2, c0 = (t & 3) * 16;
            const float* src = W + (size_t)(k0 + kr) * N + n0 + c0;
            #pragma unroll
            for (int j = 0; j < 4; ++j)
                *(float4*)&tile[kr][c0 + j * 4] = *(const float4*)(src + j * 4);
        }
        __syncthreads();
        int n = t >> 2, kc = (t & 3) * 16;
        union { ushort us[16]; float4 f4[2]; } ph, pl;
        #pragma unroll
        for (int j = 0; j < 16; ++j) {
            float v = tile[kc + j][n];
            ushort hb = f2bf(v);
            ph.us[j] = hb;
            pl.us[j] = f2bf(v - bf2f(hb));
        }
        ushort* dh = Th + (size_t)(n0 + n) * K + k0 + kc;
        *(float4*)(dh) = ph.f4[0];
        *(float4*)(dh + 8) = ph.f4[1];
        if (split) {
            ushort* dl = Tl + (size_t)(n0 + n) * K + k0 + kc;
            *(float4*)(dl) = pl.f4[0];
            *(float4*)(dl + 8) = pl.f4[1];
        }
    } else if (id < 1280) {
        int row = (id - 768) * 4 + (t >> 6);
        int lane = t & 63;
        ushort neg = f2bf(-1e9f);
        unsigned long long bal[4];
        #pragma unroll
        for (int u = 0; u < 4; ++u) {
            int base = row * SEQ + u * 512 + lane * 8;
            int4 a = *(const int4*)(mask + base);
            int4 c = *(const int4*)(mask + base + 4);
            union { ushort us[8]; float4 f4; } o;
            o.us[0] = a.x ? (ushort)0 : neg;
            o.us[1] = a.y ? (ushort)0 : neg;
            o.us[2] = a.z ? (ushort)0 : neg;
            o.us[3] = a.w ? (ushort)0 : neg;
            o.us[4] = c.x ? (ushort)0 : neg;
            o.us[5] = c.y ? (ushort)0 : neg;
            o.us[6] = c.z ? (ushort)0 : neg;
            o.us[7] = c.w ? (ushort)0 : neg;
            *(float4*)(mb + base) = o.f4;
            bool ok = a.x && a.y && a.z && a.w && c.x && c.y && c.z && c.w;
            bal[u] = __ballot(ok);
        }
        if (lane < 32) {
            int u = lane >> 3;
            unsigned long long bsel = bal[0];
            bsel = (u == 1) ? bal[1] : bsel;
            bsel = (u == 2) ? bal[2] : bsel;
            bsel = (u == 3) ? bal[3] : bsel;
            int byte = (int)((bsel >> ((lane & 7) * 8)) & 0xFFull);
            mflag[row * 32 + lane] = (byte == 0xFF) ? 1 : 0;
        }
    } else {
        ln_row<true>(x, g1, be1, xn_h, xn_l,
                     (id - 1280) * 4 + (t >> 6), t & 63);
    }
}

// ---------------------------------------------------------------------------
// 1-term MFMA GEMM, 128x128 tile, double-buffered via global_load_lds.
// ---------------------------------------------------------------------------
template<bool RELU, bool HASRES, int OUT>
__global__ __launch_bounds__(256) void mgemm(
        const ushort* __restrict__ Ah, const ushort* __restrict__ Bth,
        const float* __restrict__ bias, const float* __restrict__ resid,
        float* __restrict__ Cf, ushort* __restrict__ Cbh,
        int M, int N, int K) {
    __shared__ __align__(16) char smem[65536];
    int tid = threadIdx.x;
    int lane = tid & 63, w = tid >> 6;
    int ln31 = lane & 31, hi = lane >> 5;
    int mh = (w >> 1) * 64, nh = (w & 1) * 64;
    int gx = gridDim.x;
    int nwg = gx * gridDim.y;
    int flat = blockIdx.y * gx + blockIdx.x;
    int sid = (flat & 7) * (nwg >> 3) + (flat >> 3);
    int n0 = (sid % gx) * 128;
    int m0 = (sid / gx) * 128;

    f32x16 acc[2][2];
    #pragma unroll
    for (int i = 0; i < 2; ++i)
        #pragma unroll
        for (int j = 0; j < 2; ++j)
            #pragma unroll
            for (int r = 0; r < 16; ++r) acc[i][j][r] = 0.f;

    auto stage = [&](char* Abuf, char* Bbuf, int k0) {
        #pragma unroll
        for (int c = 0; c < 4; ++c) {
            int ch = w * 4 + c;
            int r = ch * 8 + (lane >> 3);
            int u = (lane & 7) ^ ((r >> 2) & 7);
            gl_lds16(Ah + (size_t)(m0 + r) * K + k0 + u * 8, Abuf + ch * 1024);
            gl_lds16(Bth + (size_t)(n0 + r) * K + k0 + u * 8, Bbuf + ch * 1024);
        }
    };

    char* A0 = smem;
    char* B0 = smem + 16384;
    char* A1 = smem + 32768;
    char* B1 = smem + 49152;

    stage(A0, B0, 0);
    __syncthreads();
    int nk = K / 64;
    for (int kt = 0; kt < nk; ++kt) {
        char* Ac = (kt & 1) ? A1 : A0;
        char* Bc = (kt & 1) ? B1 : B0;
        if (kt + 1 < nk)
            stage((kt & 1) ? A0 : A1, (kt & 1) ? B0 : B1, (kt + 1) * 64);
        __builtin_amdgcn_s_setprio(1);
        #pragma unroll
        for (int km = 0; km < 4; ++km) {
            int kk = km * 16 + hi * 8;
            bf16x8 ah[2], bh[2];
            ah[0] = *(bf16x8*)swzg(Ac, mh + ln31, kk);
            ah[1] = *(bf16x8*)swzg(Ac, mh + 32 + ln31, kk);
            bh[0] = *(bf16x8*)swzg(Bc, nh + ln31, kk);
            bh[1] = *(bf16x8*)swzg(Bc, nh + 32 + ln31, kk);
            #pragma unroll
            for (int mi = 0; mi < 2; ++mi)
                #pragma unroll
                for (int ni = 0; ni < 2; ++ni)
                    acc[mi][ni] = __builtin_amdgcn_mfma_f32_32x32x16_bf16(
                        ah[mi], bh[ni], acc[mi][ni], 0, 0, 0);
        }
        __builtin_amdgcn_s_setprio(0);
        __syncthreads();
    }
    float bv[2];
    bv[0] = bias[n0 + nh + ln31];
    bv[1] = bias[n0 + nh + 32 + ln31];
    #pragma unroll
    for (int mi = 0; mi < 2; ++mi)
        #pragma unroll
        for (int ni = 0; ni < 2; ++ni) {
            int n = n0 + nh + ni * 32 + ln31;
            #pragma unroll
            for (int r = 0; r < 16; ++r) {
                int m = m0 + mh + mi * 32 + (r & 3) + 8 * (r >> 2) + 4 * hi;
                float v = acc[mi][ni][r] + bv[ni];
                if (HASRES) v += resid[(size_t)m * N + n];
                if (RELU) v = fmaxf(v, 0.f);
                size_t idx = (size_t)m * N + n;
                if (OUT == 0) Cf[idx] = v;
                else Cbh[idx] = f2bf(v);
            }
        }
}

// ---------------------------------------------------------------------------
// 1-term MFMA GEMM, 64x64 tile, 32K LDS dbuf. COMB=true: A operand combined
// on the fly from FOUR attention split-K partials (exact combine math).
// ---------------------------------------------------------------------------
template<bool RELU, bool HASRES, int OUT, bool COMB>
__global__ __launch_bounds__(256) void mgemm64(
        const ushort* __restrict__ Ah, const ushort* __restrict__ Bth,
        const float* __restrict__ bias, const float* __restrict__ resid,
        float* __restrict__ Cf, ushort* __restrict__ Cbh,
        const ushort* __restrict__ p0, const ushort* __restrict__ p1,
        const ushort* __restrict__ p2, const ushort* __restrict__ p3,
        const float2* __restrict__ mlp, int M, int N, int K) {
    __shared__ __align__(16) char smem[32768];
    int tid = threadIdx.x;
    int lane = tid & 63, w = tid >> 6;
    int ln31 = lane & 31, hi = lane >> 5;
    int mh = (w >> 1) * 32, nh = (w & 1) * 32;
    int gx = gridDim.x;
    int nwg = gx * gridDim.y;
    int flat = blockIdx.y * gx + blockIdx.x;
    int sid = (flat & 7) * (nwg >> 3) + (flat >> 3);
    int n0 = (sid % gx) * 64;
    int m0 = (sid / gx) * 64;

    f32x16 acc;
    #pragma unroll
    for (int r = 0; r < 16; ++r) acc[r] = 0.f;

    auto stage = [&](char* Abuf, char* Bbuf, int k0) {
        #pragma unroll
        for (int c = 0; c < 2; ++c) {
            int ch = w * 2 + c;
            int r = ch * 8 + (lane >> 3);
            int u = (lane & 7) ^ ((r >> 2) & 7);
            if (COMB) {
                int m = m0 + r;
                int b = m >> 11, q = m & (SEQ - 1);
                int bh = b * 8 + (k0 >> 6);
                size_t pbase = ((size_t)bh * SEQ + q) * DKH + u * 8;
                union { ushort us[8]; float4 f4; } a0, a1, a2, a3, o;
                a0.f4 = *(const float4*)(p0 + pbase);
                a1.f4 = *(const float4*)(p1 + pbase);
                a2.f4 = *(const float4*)(p2 + pbase);
                a3.f4 = *(const float4*)(p3 + pbase);
                size_t mlb = (size_t)bh * SEQ + q;
                float2 e0 = mlp[mlb];
                float2 e1 = mlp[mlb + (size_t)32 * SEQ];
                float2 e2 = mlp[mlb + (size_t)64 * SEQ];
                float2 e3 = mlp[mlb + (size_t)96 * SEQ];
                float mm = fmaxf(fmaxf(e0.x, e1.x), fmaxf(e2.x, e3.x));
                float w0 = __expf(e0.x - mm), w1 = __expf(e1.x - mm);
                float w2 = __expf(e2.x - mm), w3 = __expf(e3.x - mm);
                float inv = 1.0f / (e0.y * w0 + e1.y * w1 + e2.y * w2 + e3.y * w3);
                #pragma unroll
                for (int j = 0; j < 8; ++j)
                    o.us[j] = f2bf((bf2f(a0.us[j]) * w0 + bf2f(a1.us[j]) * w1 +
                                    bf2f(a2.us[j]) * w2 + bf2f(a3.us[j]) * w3) * inv);
                *(float4*)(Abuf + ch * 1024 + lane * 16) = o.f4;
            } else {
                gl_lds16(Ah + (size_t)(m0 + r) * K + k0 + u * 8, Abuf + ch * 1024);
            }
            gl_lds16(Bth + (size_t)(n0 + r) * K + k0 + u * 8, Bbuf + ch * 1024);
        }
    };

    char* A0 = smem;
    char* B0 = smem + 8192;
    char* A1 = smem + 16384;
    char* B1 = smem + 24576;

    stage(A0, B0, 0);
    __syncthreads();
    int nk = K / 64;
    for (int kt = 0; kt < nk; ++kt) {
        char* Ac = (kt & 1) ? A1 : A0;
        char* Bc = (kt & 1) ? B1 : B0;
        if (kt + 1 < nk)
            stage((kt & 1) ? A0 : A1, (kt & 1) ? B0 : B1, (kt + 1) * 64);
        __builtin_amdgcn_s_setprio(1);
        #pragma unroll
        for (int km = 0; km < 4; ++km) {
            int kk = km * 16 + hi * 8;
            bf16x8 a = *(bf16x8*)swzg(Ac, mh + ln31, kk);
            bf16x8 b = *(bf16x8*)swzg(Bc, nh + ln31, kk);
            acc = __builtin_amdgcn_mfma_f32_32x32x16_bf16(a, b, acc, 0, 0, 0);
        }
        __builtin_amdgcn_s_setprio(0);
        __syncthreads();
    }
    float bv = bias[n0 + nh + ln31];
    int n = n0 + nh + ln31;
    #pragma unroll
    for (int r = 0; r < 16; ++r) {
        int m = m0 + mh + (r & 3) + 8 * (r >> 2) + 4 * hi;
        float v = acc[r] + bv;
        if (HASRES) v += resid[(size_t)m * N + n];
        if (RELU) v = fmaxf(v, 0.f);
        size_t idx = (size_t)m * N + n;
        if (OUT == 0) Cf[idx] = v;
        else Cbh[idx] = f2bf(v);
    }
}

// ---------------------------------------------------------------------------
// Fused QKV GEMM. Q: 3-term split in (near-fp32 compute), bf16 hi out,
// pre-scaled by 1/8. K: 1-term, plain bf16. V: 1-term, transposed v_t out.
// ---------------------------------------------------------------------------
__global__ __launch_bounds__(256) void qkv_gemm(
        const ushort* __restrict__ Ah, const ushort* __restrict__ Al,
        const ushort* __restrict__ Bth, const ushort* __restrict__ Btl,
        const float* __restrict__ bq, const float* __restrict__ bk,
        const float* __restrict__ bv_, ushort* __restrict__ q_h,
        ushort* __restrict__ k_h, ushort* __restrict__ v_t) {
    const int K = DM, N = DM;
    __shared__ __align__(16) char smem[65536];
    char* As_h = smem;
    char* Bs_h = smem + 16384;
    char* As_l = smem + 32768;
    char* Bs_l = smem + 49152;
    int tid = threadIdx.x;
    int lane = tid & 63, w = tid >> 6;
    int ln31 = lane & 31, hi = lane >> 5;
    int mh = (w >> 1) * 64, nh = (w & 1) * 64;
    int gx = gridDim.x;  // 12
    int nwg = gx * gridDim.y;
    int flat = blockIdx.y * gx + blockIdx.x;
    int sid = (flat & 7) * (nwg >> 3) + (flat >> 3);
    int n0 = (sid % gx) * 128;
    int m0 = (sid / gx) * 128;
    bool issplit = (n0 < 512);   // Q blocks only

    f32x16 acc[2][2];
    #pragma unroll
    for (int i = 0; i < 2; ++i)
        #pragma unroll
        for (int j = 0; j < 2; ++j)
            #pragma unroll
            for (int r = 0; r < 16; ++r) acc[i][j][r] = 0.f;

    for (int k0 = 0; k0 < K; k0 += 64) {
        #pragma unroll
        for (int c = 0; c < 4; ++c) {
            int ch = w * 4 + c;
            int r = ch * 8 + (lane >> 3);
            int u = (lane & 7) ^ ((r >> 2) & 7);
            gl_lds16(Ah + (size_t)(m0 + r) * K + k0 + u * 8, As_h + ch * 1024);
            gl_lds16(Bth + (size_t)(n0 + r) * K + k0 + u * 8, Bs_h + ch * 1024);
            if (issplit) {
                gl_lds16(Al + (size_t)(m0 + r) * K + k0 + u * 8, As_l + ch * 1024);
                gl_lds16(Btl + (size_t)(n0 + r) * K + k0 + u * 8, Bs_l + ch * 1024);
            }
        }
        __syncthreads();
        __builtin_amdgcn_s_setprio(1);
        #pragma unroll
        for (int km = 0; km < 4; ++km) {
            int kk = km * 16 + hi * 8;
            bf16x8 ah[2], bh[2];
            ah[0] = *(bf16x8*)swzg(As_h, mh + ln31, kk);
            ah[1] = *(bf16x8*)swzg(As_h, mh + 32 + ln31, kk);
            bh[0] = *(bf16x8*)swzg(Bs_h, nh + ln31, kk);
            bh[1] = *(bf16x8*)swzg(Bs_h, nh + 32 + ln31, kk);
            if (issplit) {
                bf16x8 al[2], bl[2];
                al[0] = *(bf16x8*)swzg(As_l, mh + ln31, kk);
                al[1] = *(bf16x8*)swzg(As_l, mh + 32 + ln31, kk);
                bl[0] = *(bf16x8*)swzg(Bs_l, nh + ln31, kk);
                bl[1] = *(bf16x8*)swzg(Bs_l, nh + 32 + ln31, kk);
                #pragma unroll
                for (int mi = 0; mi < 2; ++mi)
                    #pragma unroll
                    for (int ni = 0; ni < 2; ++ni) {
                        acc[mi][ni] = __builtin_amdgcn_mfma_f32_32x32x16_bf16(
                            ah[mi], bh[ni], acc[mi][ni], 0, 0, 0);
                        acc[mi][ni] = __builtin_amdgcn_mfma_f32_32x32x16_bf16(
                            ah[mi], bl[ni], acc[mi][ni], 0, 0, 0);
                        acc[mi][ni] = __builtin_amdgcn_mfma_f32_32x32x16_bf16(
                            al[mi], bh[ni], acc[mi][ni], 0, 0, 0);
                    }
            } else {
                #pragma unroll
                for (int mi = 0; mi < 2; ++mi)
                    #pragma unroll
                    for (int ni = 0; ni < 2; ++ni)
                        acc[mi][ni] = __builtin_amdgcn_mfma_f32_32x32x16_bf16(
                            ah[mi], bh[ni], acc[mi][ni], 0, 0, 0);
            }
        }
        __builtin_amdgcn_s_setprio(0);
        __syncthreads();
    }
    if (n0 < 512) {
        // Q: bf16 hi output, pre-scaled by 1/8
        float bvv[2];
        bvv[0] = bq[n0 + nh + ln31];
        bvv[1] = bq[n0 + nh + 32 + ln31];
        #pragma unroll
        for (int mi = 0; mi < 2; ++mi)
            #pragma unroll
            for (int ni = 0; ni < 2; ++ni) {
                int n = n0 + nh + ni * 32 + ln31;
                #pragma unroll
                for (int r = 0; r < 16; ++r) {
                    int m = m0 + mh + mi * 32 + (r & 3) + 8 * (r >> 2) + 4 * hi;
                    float v = (acc[mi][ni][r] + bvv[ni]) * 0.125f;
                    q_h[(size_t)m * N + n] = f2bf(v);
                }
            }
    } else if (n0 < 1024) {
        // K: plain bf16
        int ncol0 = n0 - 512;
        float bvv[2];
        bvv[0] = bk[ncol0 + nh + ln31];
        bvv[1] = bk[ncol0 + nh + 32 + ln31];
        #pragma unroll
        for (int mi = 0; mi < 2; ++mi)
            #pragma unroll
            for (int ni = 0; ni < 2; ++ni) {
                int n = ncol0 + nh + ni * 32 + ln31;
                #pragma unroll
                for (int r = 0; r < 16; ++r) {
                    int m = m0 + mh + mi * 32 + (r & 3) + 8 * (r >> 2) + 4 * hi;
                    k_h[(size_t)m * N + n] = f2bf(acc[mi][ni][r] + bvv[ni]);
                }
            }
    } else {
        // V: LDS round-trip, store transposed into v_t
        int ncol0 = n0 & 511;
        float bvv[2];
        bvv[0] = bv_[ncol0 + nh + ln31];
        bvv[1] = bv_[ncol0 + nh + 32 + ln31];
        __syncthreads();
        #pragma unroll
        for (int mi = 0; mi < 2; ++mi)
            #pragma unroll
            for (int ni = 0; ni < 2; ++ni) {
                int nloc = nh + ni * 32 + ln31;
                #pragma unroll
                for (int r = 0; r < 16; ++r) {
                    int mloc = mh + mi * 32 + (r & 3) + 8 * (r >> 2) + 4 * hi;
                    *(ushort*)swzv(smem, mloc, nloc) =
                        f2bf(acc[mi][ni][r] + bvv[ni]);
                }
            }
        __syncthreads();
        int nloc = tid >> 1, half = tid & 1;
        int nglob = ncol0 + nloc;
        int h = nglob >> 6, d = nglob & 63;
        int b = m0 >> 11;
        int s0 = (m0 & (SEQ - 1)) + half * 64;
        ushort* dst = v_t + (((size_t)(b * 8 + h) * DKH + d) * SEQ) + s0;
        #pragma unroll
        for (int gblk = 0; gblk < 8; ++gblk) {
            union { ushort us[8]; float4 f4; } ov;
            #pragma unroll
            for (int j = 0; j < 8; ++j)
                ov.us[j] = *(ushort*)swzv(smem, half * 64 + gblk * 8 + j, nloc);
            *(float4*)(dst + gblk * 8) = ov.f4;
        }
    }
}

// ---------------------------------------------------------------------------
// MFMA flash attention, split-K x4, QB=256 (512 threads, 8 waves).
// Q,K plain bf16 (1-term QK). LDS 32K: Q stage, then K/V double-buffer 2x16K.
// Grid 1024 blocks -> ~3 resident blocks/CU.
// ---------------------------------------------------------------------------
__global__ __launch_bounds__(512) void attn_kernel(
        const ushort* __restrict__ Qh, const ushort* __restrict__ Khg,
        const ushort* __restrict__ Vtg, const ushort* __restrict__ mb,
        const unsigned char* __restrict__ mflag,
        ushort* __restrict__ p0, ushort* __restrict__ p1,
        ushort* __restrict__ p2, ushort* __restrict__ p3,
        float2* __restrict__ ml) {
    __shared__ __align__(16) char smem[32768];
    int tid = threadIdx.x;
    int w = tid >> 6, lane = tid & 63;
    int ln31 = lane & 31, hi = lane >> 5;
    bool hib = (hi != 0);
    // 1024 blocks: 128 per XCD
    int f = blockIdx.y * gridDim.x + blockIdx.x;
    int g = (f & 7) * 128 + (f >> 3);
    int bh = g >> 5, rest = g & 31;
    int part = rest >> 3, qb = rest & 7;
    int b = bh >> 3, h = bh & 7;
    int q0 = qb * 256;
    size_t brow = (size_t)b * SEQ;
    int hcol = h * DKH;
    int ktbeg = part * 8, ktend = ktbeg + 8;

    // stage one 16KB K/V tile: 16 chunks over 8 waves (2 each).
    auto stage_kv = [&](char* buf, int kt) {
        #pragma unroll
        for (int c = 0; c < 2; ++c) {
            int q = w * 2 + c;              // 0..15
            int r = (q & 7) * 8 + (lane >> 3);
            int u = (lane & 7) ^ (r & 7);
            const ushort* src = (q < 8)
                ? Khg + (brow + kt * 64 + r) * DM + hcol + u * 8
                : Vtg + ((size_t)bh * DKH + r) * SEQ + kt * 64 + u * 8;
            gl_lds16(src, buf + q * 1024);
        }
    };

    // prologue: stage Q (256 rows, hi only = 32K), read frags
    {
        #pragma unroll
        for (int c = 0; c < 4; ++c) {
            int ch = w * 4 + c;             // 0..31
            int r = ch * 8 + (lane >> 3);   // 0..255
            int u = (lane & 7) ^ (r & 7);
            gl_lds16(Qh + (brow + q0 + r) * DM + hcol + u * 8,
                     smem + ch * 1024);
        }
    }
    __syncthreads();
    bf16x8 qfh[4];
    {
        int qr = w * 32 + ln31;
        #pragma unroll
        for (int c = 0; c < 4; ++c)
            qfh[c] = *(bf16x8*)swz(smem, qr, c * 16 + hi * 8);
    }
    __syncthreads();
    stage_kv(smem + (ktbeg & 1) * 16384, ktbeg);
    __syncthreads();

    f32x16 ctx0, ctx1;
    #pragma unroll
    for (int r = 0; r < 16; ++r) { ctx0[r] = 0.f; ctx1[r] = 0.f; }
    float m_i = -1e30f, l_i = 0.f;
    int qglob = q0 + w * 32 + ln31;
    const ushort* mrow = mb + (size_t)qglob * SEQ;

    for (int kt = ktbeg; kt < ktend; ++kt) {
        char* cur = smem + (kt & 1) * 16384;
        if (kt + 1 < ktend)
            stage_kv(smem + ((kt + 1) & 1) * 16384, kt + 1);
        unsigned char fl = mflag[qglob * 32 + kt];
        bool domask = !__all(fl != 0);
        ushort4 mpre[8];
        if (domask) {
            #pragma unroll
            for (int i = 0; i < 8; ++i)
                mpre[i] = *(const ushort4*)(mrow + kt * 64 + i * 8 + hi * 4);
        }
        char* KhL = cur;
        char* VtL = cur + 8192;
        #pragma unroll
        for (int ksub = 0; ksub < 2; ++ksub) {
            // ---- QK^T: 1-term (Q pre-scaled by 1/8) ----
            f32x16 s;
            #pragma unroll
            for (int r = 0; r < 16; ++r) s[r] = 0.f;
            __builtin_amdgcn_s_setprio(1);
            #pragma unroll
            for (int c = 0; c < 4; ++c) {
                bf16x8 ka = *(bf16x8*)swz(KhL, ksub * 32 + ln31, c * 16 + hi * 8);
                s = __builtin_amdgcn_mfma_f32_32x32x16_bf16(ka, qfh[c], s, 0, 0, 0);
            }
            __builtin_amdgcn_s_setprio(0);
            // ---- floor + mask ----
            if (domask) {
                #pragma unroll
                for (int rg = 0; rg < 4; ++rg) {
                    ushort4 mv = mpre[ksub * 4 + rg];
                    ushort mu[4] = {mv.x, mv.y, mv.z, mv.w};
                    #pragma unroll
                    for (int j = 0; j < 4; ++j) {
                        int r = rg * 4 + j;
                        s[r] = floorf(s[r]) + bf2f(mu[j]);
                    }
                }
            } else {
                #pragma unroll
                for (int r = 0; r < 16; ++r) s[r] = floorf(s[r]);
            }
            // ---- tree max ----
            float t0 = fmaxf(fmaxf(s[0], s[1]), fmaxf(s[2], s[3]));
            float t1 = fmaxf(fmaxf(s[4], s[5]), fmaxf(s[6], s[7]));
            float t2 = fmaxf(fmaxf(s[8], s[9]), fmaxf(s[10], s[11]));
            float t3 = fmaxf(fmaxf(s[12], s[13]), fmaxf(s[14], s[15]));
            float tmax = fmaxf(fmaxf(t0, t1), fmaxf(t2, t3));
            tmax = fmaxf(tmax, __shfl_xor(tmax, 32));
            if (!__all(tmax <= m_i)) {
                float newm = fmaxf(m_i, tmax);
                float scl = __expf(m_i - newm);
                m_i = newm;
                l_i *= scl;
                #pragma unroll
                for (int r = 0; r < 16; ++r) { ctx0[r] *= scl; ctx1[r] *= scl; }
            }
            #pragma unroll
            for (int r = 0; r < 16; ++r) s[r] = __expf(s[r] - m_i);
            // ---- 4-way partial psum ----
            {
                float p0s = (s[0] + s[4]) + (s[8] + s[12]);
                float p1s = (s[1] + s[5]) + (s[9] + s[13]);
                float p2s = (s[2] + s[6]) + (s[10] + s[14]);
                float p3s = (s[3] + s[7]) + (s[11] + s[15]);
                float psum = (p0s + p1s) + (p2s + p3s);
                psum += __shfl_xor(psum, 32);
                l_i += psum;
            }
            // ---- pack P and exchange across hi-halves in-reg ----
            uint pk0[4], pk1[4];
            #pragma unroll
            for (int rg = 0; rg < 4; ++rg) {
                pk0[rg] = cvtpk_bf16(s[rg * 4 + 0], s[rg * 4 + 1]);
                pk1[rg] = cvtpk_bf16(s[rg * 4 + 2], s[rg * 4 + 3]);
            }
            bf16x8 pb[2];
            #pragma unroll
            for (int cc = 0; cc < 2; ++cc) {
                uint A0 = pk0[cc * 2], A1 = pk1[cc * 2];
                uint B0 = pk0[cc * 2 + 1], B1 = pk1[cc * 2 + 1];
                uint send0 = hib ? A0 : B0;
                uint send1 = hib ? A1 : B1;
                uint own0  = hib ? B0 : A0;
                uint own1  = hib ? B1 : A1;
                uint recv0 = (uint)__shfl_xor((int)send0, 32);
                uint recv1 = (uint)__shfl_xor((int)send1, 32);
                union { uint u[4]; bf16x8 v; } pbu;
                pbu.u[0] = hib ? recv0 : own0;
                pbu.u[1] = hib ? recv1 : own1;
                pbu.u[2] = hib ? own0 : recv0;
                pbu.u[3] = hib ? own1 : recv1;
                pb[cc] = pbu.v;
            }
            // ---- PV ----
            __builtin_amdgcn_s_setprio(1);
            #pragma unroll
            for (int cc = 0; cc < 2; ++cc) {
                int c = ksub * 2 + cc;
                bf16x8 va0 = *(bf16x8*)swz(VtL, ln31, c * 16 + hi * 8);
                bf16x8 va1 = *(bf16x8*)swz(VtL, 32 + ln31, c * 16 + hi * 8);
                ctx0 = __builtin_amdgcn_mfma_f32_32x32x16_bf16(va0, pb[cc], ctx0, 0, 0, 0);
                ctx1 = __builtin_amdgcn_mfma_f32_32x32x16_bf16(va1, pb[cc], ctx1, 0, 0, 0);
            }
            __builtin_amdgcn_s_setprio(0);
        }
        __syncthreads();  // next tile staged; current fully consumed
    }

    // epilogue: write unnormalized partial ctx (bf16) + (m,l)
    ushort* P = (part == 0) ? p0 : (part == 1) ? p1 : (part == 2) ? p2 : p3;
    size_t pbase = ((size_t)bh * SEQ + qglob) * DKH;
    #pragma unroll
    for (int r = 0; r < 16; ++r) {
        int d = (r & 3) + 8 * (r >> 2) + 4 * hi;
        P[pbase + d] = f2bf(ctx0[r]);
        P[pbase + 32 + d] = f2bf(ctx1[r]);
    }
    if (hi == 0)
        ml[((size_t)part * 32 + bh) * SEQ + qglob] = make_float2(m_i, l_i);
}

// ---------------------------------------------------------------------------
extern "C" void kernel_launch(void* const* d_in, const int* in_sizes, int n_in,
                              void* d_out, int out_size, void* d_ws, size_t ws_size,
                              hipStream_t stream) {
    const float* x    = (const float*)d_in[0];
    const int*   mask = (const int*)d_in[1];
    const float* wq = (const float*)d_in[2];
    const float* bq = (const float*)d_in[3];
    const float* wk = (const float*)d_in[4];
    const float* bk = (const float*)d_in[5];
    const float* wv = (const float*)d_in[6];
    const float* bv = (const float*)d_in[7];
    const float* wo = (const float*)d_in[8];
    const float* bo = (const float*)d_in[9];
    const float* w1 = (const float*)d_in[10];
    const float* b1 = (const float*)d_in[11];
    const float* w2 = (const float*)d_in[12];
    const float* b2 = (const float*)d_in[13];
    const float* g1  = (const float*)d_in[14];
    const float* be1 = (const float*)d_in[15];
    const float* g2  = (const float*)d_in[16];
    const float* be2 = (const float*)d_in[17];
    float* out = (float*)d_out;

    char* ws = (char*)d_ws;
    const size_t MiB = 1024 * 1024;
    ushort* xn_h = (ushort*)(ws);                 // 8 MiB (dead after qkv)
    ushort* xn_l = (ushort*)(ws + 8 * MiB);       // 8 MiB (xn2 for LN2)
    ushort* q_h  = (ushort*)(ws + 16 * MiB);      // 8 MiB
    ushort* k_h  = (ushort*)(ws + 32 * MiB);      // 8 MiB
    ushort* v_t  = (ushort*)(ws + 56 * MiB);      // 8 MiB
    ushort* wqkvt_h = (ushort*)(ws + 64 * MiB);   // 1.5 MiB
    ushort* wqt_l   = (ushort*)(ws + 66 * MiB);   // 512 KiB (Q lo only)
    ushort* wot_h = (ushort*)(ws + 67 * MiB);     // 512 KiB
    unsigned char* mflag = (unsigned char*)(ws + 67 * MiB + 512 * 1024); // 64 KiB
    ushort* w1t_h = (ushort*)(ws + 68 * MiB);     // 2 MiB
    ushort* w2t_h = (ushort*)(ws + 70 * MiB);     // 2 MiB
    ushort* mb    = (ushort*)(ws + 72 * MiB);     // 8 MiB
    ushort* pctx0 = (ushort*)(ws + 80 * MiB);     // 8 MiB
    ushort* pctx1 = (ushort*)(ws + 88 * MiB);     // 8 MiB
    ushort* pctx2 = (ushort*)(ws + 40 * MiB);     // 8 MiB (free region 40-56)
    ushort* pctx3 = (ushort*)(ws + 48 * MiB);     // 8 MiB
    float2* ml    = (float2*)(ws + 96 * MiB);     // 2 MiB
    // overlays
    ushort* xn2  = xn_l;                          // after qkv
    ushort* ff1  = q_h;                           // 32 MiB over 16..48M (dead post-outproj)

    dim3 blk256(256);
    prep<<<3328, blk256, 0, stream>>>(
        wq, wk, wv, wo, w1, w2, mask, x, g1, be1,
        wqkvt_h, wqt_l, wqkvt_h + 512 * 512,
        wqkvt_h + 1024 * 512, wot_h, w1t_h, w2t_h, mb, mflag, xn_h, xn_l);
    qkv_gemm<<<dim3(12, NROWS / 128), blk256, 0, stream>>>(
        xn_h, xn_l, wqkvt_h, wqt_l, bq, bk, bv, q_h, k_h, v_t);
    {
        dim3 grid(32, 32);  // 1024 blocks: 32 bh x (4 parts x 8 qb of 256 rows)
        attn_kernel<<<grid, dim3(512), 0, stream>>>(
            q_h, k_h, v_t, mb, mflag, pctx0, pctx1, pctx2, pctx3, ml);
    }
    {
        dim3 grid(DM / 64, NROWS / 64);  // out-proj with fused 4-way combine
        mgemm64<false,true,0,true><<<grid, blk256, 0, stream>>>(
            nullptr, wot_h, bo, x, out, nullptr, pctx0, pctx1, pctx2, pctx3,
            ml, NROWS, DM, DM);
    }
    ln_kernel<false><<<NROWS / 4, blk256, 0, stream>>>(out, g2, be2, xn2, nullptr);
    {
        dim3 grid(DFF / 128, NROWS / 128);
        mgemm<true,false,1><<<grid, blk256, 0, stream>>>(
            xn2, w1t_h, b1, nullptr, nullptr, ff1, NROWS, DFF, DM);
    }
    {
        dim3 grid(DM / 64, NROWS / 64);
        mgemm64<false,true,0,false><<<grid, blk256, 0, stream>>>(
            ff1, w2t_h, b2, out, out, nullptr, nullptr, nullptr, nullptr,
            nullptr, nullptr, NROWS, DM, DFF);
    }
}

// Round 20
// 216.876 us; speedup vs baseline: 1.0662x; 1.0662x over previous
//
#include <hip/hip_runtime.h>
#include <cmath>

#define SEQ 2048
#define DM 512
#define DFF 2048
#define NH 8
#define DKH 64
#define NROWS 8192  // B*S = 4*2048

typedef __attribute__((ext_vector_type(8))) short bf16x8;
typedef __attribute__((ext_vector_type(16))) float f32x16;

__device__ __forceinline__ ushort f2bf(float f) {
    uint u = __float_as_uint(f);
    u += 0x7fff + ((u >> 16) & 1);
    return (ushort)(u >> 16);
}
__device__ __forceinline__ float bf2f(ushort h) {
    return __uint_as_float(((uint)h) << 16);
}
__device__ __forceinline__ uint cvtpk_bf16(float a, float b) {
    uint r;
    asm("v_cvt_pk_bf16_f32 %0, %1, %2" : "=v"(r) : "v"(a), "v"(b));
    return r;
}
// async global->LDS, 16B per lane. LDS dest = base + lane*16 (linear).
__device__ __forceinline__ void gl_lds16(const void* g, void* l) {
    __builtin_amdgcn_global_load_lds(
        (const __attribute__((address_space(1))) void*)g,
        (__attribute__((address_space(3))) void*)l, 16, 0, 0);
}
// 128B-row LDS swizzle (attn): byte ^= (row&7)<<4
__device__ __forceinline__ void* swz(char* base, int row, int col) {
    int byte = (row << 7) + (col << 1);
    byte ^= (row & 7) << 4;
    return base + byte;
}
// gemm LDS swizzle: byte ^= ((row>>2)&7)<<4
__device__ __forceinline__ void* swzg(char* base, int row, int k) {
    int byte = (row << 7) + (k << 1);
    byte ^= ((row >> 2) & 7) << 4;
    return base + byte;
}
// 256B-row LDS swizzle (qkv V transpose tile): byte ^= (row&7)<<4
__device__ __forceinline__ void* swzv(char* base, int row, int col) {
    int byte = (row << 8) + (col << 1);
    byte ^= (row & 7) << 4;
    return base + byte;
}

// ---------------------------------------------------------------------------
// LayerNorm core (one row per wave)
// ---------------------------------------------------------------------------
template<bool SPLIT>
__device__ __forceinline__ void ln_row(const float* __restrict__ x,
        const float* __restrict__ g, const float* __restrict__ b,
        ushort* __restrict__ oh, ushort* __restrict__ ol, int row, int t) {
    const float* xr = x + (size_t)row * DM + t * 8;
    float v[8];
    *(float4*)&v[0] = *(const float4*)(xr);
    *(float4*)&v[4] = *(const float4*)(xr + 4);
    float s = 0.f;
    #pragma unroll
    for (int j = 0; j < 8; ++j) s += v[j];
    #pragma unroll
    for (int m = 32; m > 0; m >>= 1) s += __shfl_xor(s, m);
    float mean = s * (1.0f / DM);
    float ss = 0.f;
    #pragma unroll
    for (int j = 0; j < 8; ++j) { float d = v[j] - mean; ss += d * d; }
    #pragma unroll
    for (int m = 32; m > 0; m >>= 1) ss += __shfl_xor(ss, m);
    float inv = 1.0f / (sqrtf(ss * (1.0f / (DM - 1))) + 1e-6f);
    float gv[8], bv[8];
    *(float4*)&gv[0] = *(const float4*)(g + t * 8);
    *(float4*)&gv[4] = *(const float4*)(g + t * 8 + 4);
    *(float4*)&bv[0] = *(const float4*)(b + t * 8);
    *(float4*)&bv[4] = *(const float4*)(b + t * 8 + 4);
    union { ushort us[8]; float4 f4; } ph, pl;
    #pragma unroll
    for (int j = 0; j < 8; ++j) {
        float o = gv[j] * (v[j] - mean) * inv + bv[j];
        ushort hb = f2bf(o);
        ph.us[j] = hb;
        if (SPLIT) pl.us[j] = f2bf(o - bf2f(hb));
    }
    *(float4*)(oh + (size_t)row * DM + t * 8) = ph.f4;
    if (SPLIT) *(float4*)(ol + (size_t)row * DM + t * 8) = pl.f4;
}

template<bool SPLIT>
__global__ __launch_bounds__(256) void ln_kernel(const float* __restrict__ x,
        const float* __restrict__ g, const float* __restrict__ b,
        ushort* __restrict__ oh, ushort* __restrict__ ol) {
    ln_row<SPLIT>(x, g, b, oh, ol, blockIdx.x * 4 + (threadIdx.x >> 6),
                  threadIdx.x & 63);
}

// ---------------------------------------------------------------------------
// Merged prep: 6 weight transposes + mask bias/flags + LN1, ONE launch.
// Only wq gets a lo (split) copy; all others plain bf16.
// ---------------------------------------------------------------------------
__global__ __launch_bounds__(256) void prep(
        const float* __restrict__ wq, const float* __restrict__ wk,
        const float* __restrict__ wv, const float* __restrict__ wo,
        const float* __restrict__ w1, const float* __restrict__ w2,
        const int* __restrict__ mask, const float* __restrict__ x,
        const float* __restrict__ g1, const float* __restrict__ be1,
        ushort* __restrict__ qh, ushort* __restrict__ ql,
        ushort* __restrict__ kh, ushort* __restrict__ vh,
        ushort* __restrict__ oh,
        ushort* __restrict__ w1t, ushort* __restrict__ w2t,
        ushort* __restrict__ mb, unsigned char* __restrict__ mflag,
        ushort* __restrict__ xn_h, ushort* __restrict__ xn_l) {
    __shared__ float tile[64][65];
    int id = blockIdx.x;
    int t = threadIdx.x;
    if (id < 768) {
        const float* W;
        ushort* Th;
        ushort* Tl = nullptr;
        int K, N, k0, n0;
        bool split = false;
        if (id < 256) {
            int z = id >> 6, r = id & 63;
            W = (z == 0) ? wq : (z == 1) ? wk : (z == 2) ? wv : wo;
            Th = (z == 0) ? qh : (z == 1) ? kh : (z == 2) ? vh : oh;
            Tl = (z == 0) ? ql : nullptr;
            split = (z == 0);
            K = DM; N = DM;
            k0 = (r >> 3) * 64; n0 = (r & 7) * 64;
        } else if (id < 512) {
            int r = id - 256;
            W = w1; Th = w1t; K = DM; N = DFF;
            k0 = (r & 7) * 64; n0 = (r >> 3) * 64;
        } else {
            int r = id - 512;
            W = w2; Th = w2t; K = DFF; N = DM;
            k0 = (r & 31) * 64; n0 = (r >> 5) * 64;
        }
        {
            int kr = t >> 2, c0 = (t & 3) * 16;
            const float* src = W + (size_t)(k0 + kr) * N + n0 + c0;
            #pragma unroll
            for (int j = 0; j < 4; ++j)
                *(float4*)&tile[kr][c0 + j * 4] = *(const float4*)(src + j * 4);
        }
        __syncthreads();
        int n = t >> 2, kc = (t & 3) * 16;
        union { ushort us[16]; float4 f4[2]; } ph, pl;
        #pragma unroll
        for (int j = 0; j < 16; ++j) {
            float v = tile[kc + j][n];
            ushort hb = f2bf(v);
            ph.us[j] = hb;
            pl.us[j] = f2bf(v - bf2f(hb));
        }
        ushort* dh = Th + (size_t)(n0 + n) * K + k0 + kc;
        *(float4*)(dh) = ph.f4[0];
        *(float4*)(dh + 8) = ph.f4[1];
        if (split) {
            ushort* dl = Tl + (size_t)(n0 + n) * K + k0 + kc;
            *(float4*)(dl) = pl.f4[0];
            *(float4*)(dl + 8) = pl.f4[1];
        }
    } else if (id < 1280) {
        int row = (id - 768) * 4 + (t >> 6);
        int lane = t & 63;
        ushort neg = f2bf(-1e9f);
        unsigned long long bal[4];
        #pragma unroll
        for (int u = 0; u < 4; ++u) {
            int base = row * SEQ + u * 512 + lane * 8;
            int4 a = *(const int4*)(mask + base);
            int4 c = *(const int4*)(mask + base + 4);
            union { ushort us[8]; float4 f4; } o;
            o.us[0] = a.x ? (ushort)0 : neg;
            o.us[1] = a.y ? (ushort)0 : neg;
            o.us[2] = a.z ? (ushort)0 : neg;
            o.us[3] = a.w ? (ushort)0 : neg;
            o.us[4] = c.x ? (ushort)0 : neg;
            o.us[5] = c.y ? (ushort)0 : neg;
            o.us[6] = c.z ? (ushort)0 : neg;
            o.us[7] = c.w ? (ushort)0 : neg;
            *(float4*)(mb + base) = o.f4;
            bool ok = a.x && a.y && a.z && a.w && c.x && c.y && c.z && c.w;
            bal[u] = __ballot(ok);
        }
        if (lane < 32) {
            int u = lane >> 3;
            unsigned long long bsel = bal[0];
            bsel = (u == 1) ? bal[1] : bsel;
            bsel = (u == 2) ? bal[2] : bsel;
            bsel = (u == 3) ? bal[3] : bsel;
            int byte = (int)((bsel >> ((lane & 7) * 8)) & 0xFFull);
            mflag[row * 32 + lane] = (byte == 0xFF) ? 1 : 0;
        }
    } else {
        ln_row<true>(x, g1, be1, xn_h, xn_l,
                     (id - 1280) * 4 + (t >> 6), t & 63);
    }
}

// ---------------------------------------------------------------------------
// 1-term MFMA GEMM, 128x128 tile, double-buffered via global_load_lds.
// ---------------------------------------------------------------------------
template<bool RELU, bool HASRES, int OUT>
__global__ __launch_bounds__(256) void mgemm(
        const ushort* __restrict__ Ah, const ushort* __restrict__ Bth,
        const float* __restrict__ bias, const float* __restrict__ resid,
        float* __restrict__ Cf, ushort* __restrict__ Cbh,
        int M, int N, int K) {
    __shared__ __align__(16) char smem[65536];
    int tid = threadIdx.x;
    int lane = tid & 63, w = tid >> 6;
    int ln31 = lane & 31, hi = lane >> 5;
    int mh = (w >> 1) * 64, nh = (w & 1) * 64;
    int gx = gridDim.x;
    int nwg = gx * gridDim.y;
    int flat = blockIdx.y * gx + blockIdx.x;
    int sid = (flat & 7) * (nwg >> 3) + (flat >> 3);
    int n0 = (sid % gx) * 128;
    int m0 = (sid / gx) * 128;

    f32x16 acc[2][2];
    #pragma unroll
    for (int i = 0; i < 2; ++i)
        #pragma unroll
        for (int j = 0; j < 2; ++j)
            #pragma unroll
            for (int r = 0; r < 16; ++r) acc[i][j][r] = 0.f;

    auto stage = [&](char* Abuf, char* Bbuf, int k0) {
        #pragma unroll
        for (int c = 0; c < 4; ++c) {
            int ch = w * 4 + c;
            int r = ch * 8 + (lane >> 3);
            int u = (lane & 7) ^ ((r >> 2) & 7);
            gl_lds16(Ah + (size_t)(m0 + r) * K + k0 + u * 8, Abuf + ch * 1024);
            gl_lds16(Bth + (size_t)(n0 + r) * K + k0 + u * 8, Bbuf + ch * 1024);
        }
    };

    char* A0 = smem;
    char* B0 = smem + 16384;
    char* A1 = smem + 32768;
    char* B1 = smem + 49152;

    stage(A0, B0, 0);
    __syncthreads();
    int nk = K / 64;
    for (int kt = 0; kt < nk; ++kt) {
        char* Ac = (kt & 1) ? A1 : A0;
        char* Bc = (kt & 1) ? B1 : B0;
        if (kt + 1 < nk)
            stage((kt & 1) ? A0 : A1, (kt & 1) ? B0 : B1, (kt + 1) * 64);
        __builtin_amdgcn_s_setprio(1);
        #pragma unroll
        for (int km = 0; km < 4; ++km) {
            int kk = km * 16 + hi * 8;
            bf16x8 ah[2], bh[2];
            ah[0] = *(bf16x8*)swzg(Ac, mh + ln31, kk);
            ah[1] = *(bf16x8*)swzg(Ac, mh + 32 + ln31, kk);
            bh[0] = *(bf16x8*)swzg(Bc, nh + ln31, kk);
            bh[1] = *(bf16x8*)swzg(Bc, nh + 32 + ln31, kk);
            #pragma unroll
            for (int mi = 0; mi < 2; ++mi)
                #pragma unroll
                for (int ni = 0; ni < 2; ++ni)
                    acc[mi][ni] = __builtin_amdgcn_mfma_f32_32x32x16_bf16(
                        ah[mi], bh[ni], acc[mi][ni], 0, 0, 0);
        }
        __builtin_amdgcn_s_setprio(0);
        __syncthreads();
    }
    float bv[2];
    bv[0] = bias[n0 + nh + ln31];
    bv[1] = bias[n0 + nh + 32 + ln31];
    #pragma unroll
    for (int mi = 0; mi < 2; ++mi)
        #pragma unroll
        for (int ni = 0; ni < 2; ++ni) {
            int n = n0 + nh + ni * 32 + ln31;
            #pragma unroll
            for (int r = 0; r < 16; ++r) {
                int m = m0 + mh + mi * 32 + (r & 3) + 8 * (r >> 2) + 4 * hi;
                float v = acc[mi][ni][r] + bv[ni];
                if (HASRES) v += resid[(size_t)m * N + n];
                if (RELU) v = fmaxf(v, 0.f);
                size_t idx = (size_t)m * N + n;
                if (OUT == 0) Cf[idx] = v;
                else Cbh[idx] = f2bf(v);
            }
        }
}

// ---------------------------------------------------------------------------
// 1-term MFMA GEMM, 64x64 tile, 32K LDS dbuf. COMB=true: A operand combined
// on the fly from attention split-K partials (exact combine math).
// ---------------------------------------------------------------------------
template<bool RELU, bool HASRES, int OUT, bool COMB>
__global__ __launch_bounds__(256) void mgemm64(
        const ushort* __restrict__ Ah, const ushort* __restrict__ Bth,
        const float* __restrict__ bias, const float* __restrict__ resid,
        float* __restrict__ Cf, ushort* __restrict__ Cbh,
        const ushort* __restrict__ p0, const ushort* __restrict__ p1,
        const float2* __restrict__ mlp, int M, int N, int K) {
    __shared__ __align__(16) char smem[32768];
    int tid = threadIdx.x;
    int lane = tid & 63, w = tid >> 6;
    int ln31 = lane & 31, hi = lane >> 5;
    int mh = (w >> 1) * 32, nh = (w & 1) * 32;
    int gx = gridDim.x;
    int nwg = gx * gridDim.y;
    int flat = blockIdx.y * gx + blockIdx.x;
    int sid = (flat & 7) * (nwg >> 3) + (flat >> 3);
    int n0 = (sid % gx) * 64;
    int m0 = (sid / gx) * 64;

    f32x16 acc;
    #pragma unroll
    for (int r = 0; r < 16; ++r) acc[r] = 0.f;

    auto stage = [&](char* Abuf, char* Bbuf, int k0) {
        #pragma unroll
        for (int c = 0; c < 2; ++c) {
            int ch = w * 2 + c;
            int r = ch * 8 + (lane >> 3);
            int u = (lane & 7) ^ ((r >> 2) & 7);
            if (COMB) {
                int m = m0 + r;
                int b = m >> 11, q = m & (SEQ - 1);
                int bh = b * 8 + (k0 >> 6);
                size_t pbase = ((size_t)bh * SEQ + q) * DKH + u * 8;
                union { ushort us[8]; float4 f4; } a0, a1, o;
                a0.f4 = *(const float4*)(p0 + pbase);
                a1.f4 = *(const float4*)(p1 + pbase);
                float2 e0 = mlp[(size_t)bh * SEQ + q];
                float2 e1 = mlp[((size_t)32 + bh) * SEQ + q];
                float mm = fmaxf(e0.x, e1.x);
                float w0 = __expf(e0.x - mm), w1 = __expf(e1.x - mm);
                float inv = 1.0f / (e0.y * w0 + e1.y * w1);
                #pragma unroll
                for (int j = 0; j < 8; ++j)
                    o.us[j] = f2bf((bf2f(a0.us[j]) * w0 + bf2f(a1.us[j]) * w1) * inv);
                *(float4*)(Abuf + ch * 1024 + lane * 16) = o.f4;
            } else {
                gl_lds16(Ah + (size_t)(m0 + r) * K + k0 + u * 8, Abuf + ch * 1024);
            }
            gl_lds16(Bth + (size_t)(n0 + r) * K + k0 + u * 8, Bbuf + ch * 1024);
        }
    };

    char* A0 = smem;
    char* B0 = smem + 8192;
    char* A1 = smem + 16384;
    char* B1 = smem + 24576;

    stage(A0, B0, 0);
    __syncthreads();
    int nk = K / 64;
    for (int kt = 0; kt < nk; ++kt) {
        char* Ac = (kt & 1) ? A1 : A0;
        char* Bc = (kt & 1) ? B1 : B0;
        if (kt + 1 < nk)
            stage((kt & 1) ? A0 : A1, (kt & 1) ? B0 : B1, (kt + 1) * 64);
        __builtin_amdgcn_s_setprio(1);
        #pragma unroll
        for (int km = 0; km < 4; ++km) {
            int kk = km * 16 + hi * 8;
            bf16x8 a = *(bf16x8*)swzg(Ac, mh + ln31, kk);
            bf16x8 b = *(bf16x8*)swzg(Bc, nh + ln31, kk);
            acc = __builtin_amdgcn_mfma_f32_32x32x16_bf16(a, b, acc, 0, 0, 0);
        }
        __builtin_amdgcn_s_setprio(0);
        __syncthreads();
    }
    float bv = bias[n0 + nh + ln31];
    int n = n0 + nh + ln31;
    #pragma unroll
    for (int r = 0; r < 16; ++r) {
        int m = m0 + mh + (r & 3) + 8 * (r >> 2) + 4 * hi;
        float v = acc[r] + bv;
        if (HASRES) v += resid[(size_t)m * N + n];
        if (RELU) v = fmaxf(v, 0.f);
        size_t idx = (size_t)m * N + n;
        if (OUT == 0) Cf[idx] = v;
        else Cbh[idx] = f2bf(v);
    }
}

// ---------------------------------------------------------------------------
// Fused QKV GEMM. Q: 3-term split in (near-fp32 compute), bf16 hi out,
// pre-scaled by 1/8. K: 1-term, plain bf16. V: 1-term, transposed v_t out.
// ---------------------------------------------------------------------------
__global__ __launch_bounds__(256) void qkv_gemm(
        const ushort* __restrict__ Ah, const ushort* __restrict__ Al,
        const ushort* __restrict__ Bth, const ushort* __restrict__ Btl,
        const float* __restrict__ bq, const float* __restrict__ bk,
        const float* __restrict__ bv_, ushort* __restrict__ q_h,
        ushort* __restrict__ k_h, ushort* __restrict__ v_t) {
    const int K = DM, N = DM;
    __shared__ __align__(16) char smem[65536];
    char* As_h = smem;
    char* Bs_h = smem + 16384;
    char* As_l = smem + 32768;
    char* Bs_l = smem + 49152;
    int tid = threadIdx.x;
    int lane = tid & 63, w = tid >> 6;
    int ln31 = lane & 31, hi = lane >> 5;
    int mh = (w >> 1) * 64, nh = (w & 1) * 64;
    int gx = gridDim.x;  // 12
    int nwg = gx * gridDim.y;
    int flat = blockIdx.y * gx + blockIdx.x;
    int sid = (flat & 7) * (nwg >> 3) + (flat >> 3);
    int n0 = (sid % gx) * 128;
    int m0 = (sid / gx) * 128;
    bool issplit = (n0 < 512);   // Q blocks only

    f32x16 acc[2][2];
    #pragma unroll
    for (int i = 0; i < 2; ++i)
        #pragma unroll
        for (int j = 0; j < 2; ++j)
            #pragma unroll
            for (int r = 0; r < 16; ++r) acc[i][j][r] = 0.f;

    for (int k0 = 0; k0 < K; k0 += 64) {
        #pragma unroll
        for (int c = 0; c < 4; ++c) {
            int ch = w * 4 + c;
            int r = ch * 8 + (lane >> 3);
            int u = (lane & 7) ^ ((r >> 2) & 7);
            gl_lds16(Ah + (size_t)(m0 + r) * K + k0 + u * 8, As_h + ch * 1024);
            gl_lds16(Bth + (size_t)(n0 + r) * K + k0 + u * 8, Bs_h + ch * 1024);
            if (issplit) {
                gl_lds16(Al + (size_t)(m0 + r) * K + k0 + u * 8, As_l + ch * 1024);
                gl_lds16(Btl + (size_t)(n0 + r) * K + k0 + u * 8, Bs_l + ch * 1024);
            }
        }
        __syncthreads();
        __builtin_amdgcn_s_setprio(1);
        #pragma unroll
        for (int km = 0; km < 4; ++km) {
            int kk = km * 16 + hi * 8;
            bf16x8 ah[2], bh[2];
            ah[0] = *(bf16x8*)swzg(As_h, mh + ln31, kk);
            ah[1] = *(bf16x8*)swzg(As_h, mh + 32 + ln31, kk);
            bh[0] = *(bf16x8*)swzg(Bs_h, nh + ln31, kk);
            bh[1] = *(bf16x8*)swzg(Bs_h, nh + 32 + ln31, kk);
            if (issplit) {
                bf16x8 al[2], bl[2];
                al[0] = *(bf16x8*)swzg(As_l, mh + ln31, kk);
                al[1] = *(bf16x8*)swzg(As_l, mh + 32 + ln31, kk);
                bl[0] = *(bf16x8*)swzg(Bs_l, nh + ln31, kk);
                bl[1] = *(bf16x8*)swzg(Bs_l, nh + 32 + ln31, kk);
                #pragma unroll
                for (int mi = 0; mi < 2; ++mi)
                    #pragma unroll
                    for (int ni = 0; ni < 2; ++ni) {
                        acc[mi][ni] = __builtin_amdgcn_mfma_f32_32x32x16_bf16(
                            ah[mi], bh[ni], acc[mi][ni], 0, 0, 0);
                        acc[mi][ni] = __builtin_amdgcn_mfma_f32_32x32x16_bf16(
                            ah[mi], bl[ni], acc[mi][ni], 0, 0, 0);
                        acc[mi][ni] = __builtin_amdgcn_mfma_f32_32x32x16_bf16(
                            al[mi], bh[ni], acc[mi][ni], 0, 0, 0);
                    }
            } else {
                #pragma unroll
                for (int mi = 0; mi < 2; ++mi)
                    #pragma unroll
                    for (int ni = 0; ni < 2; ++ni)
                        acc[mi][ni] = __builtin_amdgcn_mfma_f32_32x32x16_bf16(
                            ah[mi], bh[ni], acc[mi][ni], 0, 0, 0);
            }
        }
        __builtin_amdgcn_s_setprio(0);
        __syncthreads();
    }
    if (n0 < 512) {
        // Q: bf16 hi output, pre-scaled by 1/8
        float bvv[2];
        bvv[0] = bq[n0 + nh + ln31];
        bvv[1] = bq[n0 + nh + 32 + ln31];
        #pragma unroll
        for (int mi = 0; mi < 2; ++mi)
            #pragma unroll
            for (int ni = 0; ni < 2; ++ni) {
                int n = n0 + nh + ni * 32 + ln31;
                #pragma unroll
                for (int r = 0; r < 16; ++r) {
                    int m = m0 + mh + mi * 32 + (r & 3) + 8 * (r >> 2) + 4 * hi;
                    float v = (acc[mi][ni][r] + bvv[ni]) * 0.125f;
                    q_h[(size_t)m * N + n] = f2bf(v);
                }
            }
    } else if (n0 < 1024) {
        // K: plain bf16
        int ncol0 = n0 - 512;
        float bvv[2];
        bvv[0] = bk[ncol0 + nh + ln31];
        bvv[1] = bk[ncol0 + nh + 32 + ln31];
        #pragma unroll
        for (int mi = 0; mi < 2; ++mi)
            #pragma unroll
            for (int ni = 0; ni < 2; ++ni) {
                int n = ncol0 + nh + ni * 32 + ln31;
                #pragma unroll
                for (int r = 0; r < 16; ++r) {
                    int m = m0 + mh + mi * 32 + (r & 3) + 8 * (r >> 2) + 4 * hi;
                    k_h[(size_t)m * N + n] = f2bf(acc[mi][ni][r] + bvv[ni]);
                }
            }
    } else {
        // V: LDS round-trip, store transposed into v_t
        int ncol0 = n0 & 511;
        float bvv[2];
        bvv[0] = bv_[ncol0 + nh + ln31];
        bvv[1] = bv_[ncol0 + nh + 32 + ln31];
        __syncthreads();
        #pragma unroll
        for (int mi = 0; mi < 2; ++mi)
            #pragma unroll
            for (int ni = 0; ni < 2; ++ni) {
                int nloc = nh + ni * 32 + ln31;
                #pragma unroll
                for (int r = 0; r < 16; ++r) {
                    int mloc = mh + mi * 32 + (r & 3) + 8 * (r >> 2) + 4 * hi;
                    *(ushort*)swzv(smem, mloc, nloc) =
                        f2bf(acc[mi][ni][r] + bvv[ni]);
                }
            }
        __syncthreads();
        int nloc = tid >> 1, half = tid & 1;
        int nglob = ncol0 + nloc;
        int h = nglob >> 6, d = nglob & 63;
        int b = m0 >> 11;
        int s0 = (m0 & (SEQ - 1)) + half * 64;
        ushort* dst = v_t + (((size_t)(b * 8 + h) * DKH + d) * SEQ) + s0;
        #pragma unroll
        for (int gblk = 0; gblk < 8; ++gblk) {
            union { ushort us[8]; float4 f4; } ov;
            #pragma unroll
            for (int j = 0; j < 8; ++j)
                ov.us[j] = *(ushort*)swzv(smem, half * 64 + gblk * 8 + j, nloc);
            *(float4*)(dst + gblk * 8) = ov.f4;
        }
    }
}

// ---------------------------------------------------------------------------
// MFMA flash attention, split-K x2, QB=256 (512 threads, 8 waves).
// Q and K plain bf16 -> 1-term QK (4 MFMA/ksub). LDS: Q stage 32K, then
// K/V double-buffer 2x16K in the same 32K block.
// ---------------------------------------------------------------------------
__global__ __launch_bounds__(512) void attn_kernel(
        const ushort* __restrict__ Qh, const ushort* __restrict__ Khg,
        const ushort* __restrict__ Vtg, const ushort* __restrict__ mb,
        const unsigned char* __restrict__ mflag,
        ushort* __restrict__ pctx0, ushort* __restrict__ pctx1,
        float2* __restrict__ ml) {
    __shared__ __align__(16) char smem[32768];
    int tid = threadIdx.x;
    int w = tid >> 6, lane = tid & 63;
    int ln31 = lane & 31, hi = lane >> 5;
    bool hib = (hi != 0);
    int f = blockIdx.y * gridDim.x + blockIdx.x;
    int g = (f & 7) * 64 + (f >> 3);
    int bh = g >> 4, rest = g & 15;
    int part = rest >> 3, qb = rest & 7;
    int b = bh >> 3, h = bh & 7;
    int q0 = qb * 256;
    size_t brow = (size_t)b * SEQ;
    int hcol = h * DKH;
    int ktbeg = part * 16, ktend = ktbeg + 16;

    // stage one 16KB K/V tile: 16 chunks over 8 waves (2 each).
    auto stage_kv = [&](char* buf, int kt) {
        #pragma unroll
        for (int c = 0; c < 2; ++c) {
            int q = w * 2 + c;              // 0..15
            int r = (q & 7) * 8 + (lane >> 3);
            int u = (lane & 7) ^ (r & 7);
            const ushort* src = (q < 8)
                ? Khg + (brow + kt * 64 + r) * DM + hcol + u * 8
                : Vtg + ((size_t)bh * DKH + r) * SEQ + kt * 64 + u * 8;
            gl_lds16(src, buf + q * 1024);
        }
    };

    // prologue: stage Q (256 rows, hi only = 32K), read frags
    {
        #pragma unroll
        for (int c = 0; c < 4; ++c) {
            int ch = w * 4 + c;             // 0..31
            int r = ch * 8 + (lane >> 3);   // 0..255
            int u = (lane & 7) ^ (r & 7);
            gl_lds16(Qh + (brow + q0 + r) * DM + hcol + u * 8,
                     smem + ch * 1024);
        }
    }
    __syncthreads();
    bf16x8 qfh[4];
    {
        int qr = w * 32 + ln31;
        #pragma unroll
        for (int c = 0; c < 4; ++c)
            qfh[c] = *(bf16x8*)swz(smem, qr, c * 16 + hi * 8);
    }
    __syncthreads();
    stage_kv(smem + (ktbeg & 1) * 16384, ktbeg);
    __syncthreads();

    f32x16 ctx0, ctx1;
    #pragma unroll
    for (int r = 0; r < 16; ++r) { ctx0[r] = 0.f; ctx1[r] = 0.f; }
    float m_i = -1e30f, l_i = 0.f;
    int qglob = q0 + w * 32 + ln31;
    const ushort* mrow = mb + (size_t)qglob * SEQ;

    for (int kt = ktbeg; kt < ktend; ++kt) {
        char* cur = smem + (kt & 1) * 16384;
        if (kt + 1 < ktend)
            stage_kv(smem + ((kt + 1) & 1) * 16384, kt + 1);
        unsigned char fl = mflag[qglob * 32 + kt];
        bool domask = !__all(fl != 0);
        ushort4 mpre[8];
        if (domask) {
            #pragma unroll
            for (int i = 0; i < 8; ++i)
                mpre[i] = *(const ushort4*)(mrow + kt * 64 + i * 8 + hi * 4);
        }
        char* KhL = cur;
        char* VtL = cur + 8192;
        #pragma unroll
        for (int ksub = 0; ksub < 2; ++ksub) {
            // ---- QK^T: 1-term (Q pre-scaled by 1/8) ----
            f32x16 s;
            #pragma unroll
            for (int r = 0; r < 16; ++r) s[r] = 0.f;
            __builtin_amdgcn_s_setprio(1);
            #pragma unroll
            for (int c = 0; c < 4; ++c) {
                bf16x8 ka = *(bf16x8*)swz(KhL, ksub * 32 + ln31, c * 16 + hi * 8);
                s = __builtin_amdgcn_mfma_f32_32x32x16_bf16(ka, qfh[c], s, 0, 0, 0);
            }
            __builtin_amdgcn_s_setprio(0);
            // ---- floor + mask ----
            if (domask) {
                #pragma unroll
                for (int rg = 0; rg < 4; ++rg) {
                    ushort4 mv = mpre[ksub * 4 + rg];
                    ushort mu[4] = {mv.x, mv.y, mv.z, mv.w};
                    #pragma unroll
                    for (int j = 0; j < 4; ++j) {
                        int r = rg * 4 + j;
                        s[r] = floorf(s[r]) + bf2f(mu[j]);
                    }
                }
            } else {
                #pragma unroll
                for (int r = 0; r < 16; ++r) s[r] = floorf(s[r]);
            }
            // ---- tree max ----
            float t0 = fmaxf(fmaxf(s[0], s[1]), fmaxf(s[2], s[3]));
            float t1 = fmaxf(fmaxf(s[4], s[5]), fmaxf(s[6], s[7]));
            float t2 = fmaxf(fmaxf(s[8], s[9]), fmaxf(s[10], s[11]));
            float t3 = fmaxf(fmaxf(s[12], s[13]), fmaxf(s[14], s[15]));
            float tmax = fmaxf(fmaxf(t0, t1), fmaxf(t2, t3));
            tmax = fmaxf(tmax, __shfl_xor(tmax, 32));
            if (!__all(tmax <= m_i)) {
                float newm = fmaxf(m_i, tmax);
                float scl = __expf(m_i - newm);
                m_i = newm;
                l_i *= scl;
                #pragma unroll
                for (int r = 0; r < 16; ++r) { ctx0[r] *= scl; ctx1[r] *= scl; }
            }
            #pragma unroll
            for (int r = 0; r < 16; ++r) s[r] = __expf(s[r] - m_i);
            // ---- 4-way partial psum ----
            {
                float p0 = (s[0] + s[4]) + (s[8] + s[12]);
                float p1 = (s[1] + s[5]) + (s[9] + s[13]);
                float p2 = (s[2] + s[6]) + (s[10] + s[14]);
                float p3 = (s[3] + s[7]) + (s[11] + s[15]);
                float psum = (p0 + p1) + (p2 + p3);
                psum += __shfl_xor(psum, 32);
                l_i += psum;
            }
            // ---- pack P and exchange across hi-halves in-reg ----
            uint pk0[4], pk1[4];
            #pragma unroll
            for (int rg = 0; rg < 4; ++rg) {
                pk0[rg] = cvtpk_bf16(s[rg * 4 + 0], s[rg * 4 + 1]);
                pk1[rg] = cvtpk_bf16(s[rg * 4 + 2], s[rg * 4 + 3]);
            }
            bf16x8 pb[2];
            #pragma unroll
            for (int cc = 0; cc < 2; ++cc) {
                uint A0 = pk0[cc * 2], A1 = pk1[cc * 2];
                uint B0 = pk0[cc * 2 + 1], B1 = pk1[cc * 2 + 1];
                uint send0 = hib ? A0 : B0;
                uint send1 = hib ? A1 : B1;
                uint own0  = hib ? B0 : A0;
                uint own1  = hib ? B1 : A1;
                uint recv0 = (uint)__shfl_xor((int)send0, 32);
                uint recv1 = (uint)__shfl_xor((int)send1, 32);
                union { uint u[4]; bf16x8 v; } pbu;
                pbu.u[0] = hib ? recv0 : own0;
                pbu.u[1] = hib ? recv1 : own1;
                pbu.u[2] = hib ? own0 : recv0;
                pbu.u[3] = hib ? own1 : recv1;
                pb[cc] = pbu.v;
            }
            // ---- PV ----
            __builtin_amdgcn_s_setprio(1);
            #pragma unroll
            for (int cc = 0; cc < 2; ++cc) {
                int c = ksub * 2 + cc;
                bf16x8 va0 = *(bf16x8*)swz(VtL, ln31, c * 16 + hi * 8);
                bf16x8 va1 = *(bf16x8*)swz(VtL, 32 + ln31, c * 16 + hi * 8);
                ctx0 = __builtin_amdgcn_mfma_f32_32x32x16_bf16(va0, pb[cc], ctx0, 0, 0, 0);
                ctx1 = __builtin_amdgcn_mfma_f32_32x32x16_bf16(va1, pb[cc], ctx1, 0, 0, 0);
            }
            __builtin_amdgcn_s_setprio(0);
        }
        __syncthreads();  // next tile staged; current fully consumed
    }

    // epilogue: write unnormalized partial ctx (bf16) + (m,l)
    ushort* P = part ? pctx1 : pctx0;
    size_t pbase = ((size_t)bh * SEQ + qglob) * DKH;
    #pragma unroll
    for (int r = 0; r < 16; ++r) {
        int d = (r & 3) + 8 * (r >> 2) + 4 * hi;
        P[pbase + d] = f2bf(ctx0[r]);
        P[pbase + 32 + d] = f2bf(ctx1[r]);
    }
    if (hi == 0)
        ml[((size_t)part * 32 + bh) * SEQ + qglob] = make_float2(m_i, l_i);
}

// ---------------------------------------------------------------------------
extern "C" void kernel_launch(void* const* d_in, const int* in_sizes, int n_in,
                              void* d_out, int out_size, void* d_ws, size_t ws_size,
                              hipStream_t stream) {
    const float* x    = (const float*)d_in[0];
    const int*   mask = (const int*)d_in[1];
    const float* wq = (const float*)d_in[2];
    const float* bq = (const float*)d_in[3];
    const float* wk = (const float*)d_in[4];
    const float* bk = (const float*)d_in[5];
    const float* wv = (const float*)d_in[6];
    const float* bv = (const float*)d_in[7];
    const float* wo = (const float*)d_in[8];
    const float* bo = (const float*)d_in[9];
    const float* w1 = (const float*)d_in[10];
    const float* b1 = (const float*)d_in[11];
    const float* w2 = (const float*)d_in[12];
    const float* b2 = (const float*)d_in[13];
    const float* g1  = (const float*)d_in[14];
    const float* be1 = (const float*)d_in[15];
    const float* g2  = (const float*)d_in[16];
    const float* be2 = (const float*)d_in[17];
    float* out = (float*)d_out;

    char* ws = (char*)d_ws;
    const size_t MiB = 1024 * 1024;
    ushort* xn_h = (ushort*)(ws);                 // 8 MiB
    ushort* xn_l = (ushort*)(ws + 8 * MiB);       // 8 MiB
    ushort* q_h  = (ushort*)(ws + 16 * MiB);      // 8 MiB
    ushort* k_h  = (ushort*)(ws + 32 * MiB);      // 8 MiB
    ushort* v_t  = (ushort*)(ws + 56 * MiB);      // 8 MiB
    ushort* wqkvt_h = (ushort*)(ws + 64 * MiB);   // 1.5 MiB
    ushort* wqt_l   = (ushort*)(ws + 66 * MiB);   // 512 KiB (Q lo only)
    ushort* wot_h = (ushort*)(ws + 67 * MiB);     // 512 KiB
    unsigned char* mflag = (unsigned char*)(ws + 67 * MiB + 512 * 1024); // 64 KiB
    ushort* w1t_h = (ushort*)(ws + 68 * MiB);     // 2 MiB
    ushort* w2t_h = (ushort*)(ws + 70 * MiB);     // 2 MiB
    ushort* mb    = (ushort*)(ws + 72 * MiB);     // 8 MiB
    ushort* pctx0 = (ushort*)(ws + 80 * MiB);     // 8 MiB
    ushort* pctx1 = (ushort*)(ws + 88 * MiB);     // 8 MiB
    float2* ml    = (float2*)(ws + 96 * MiB);     // 1 MiB
    // overlays
    ushort* xn2  = xn_l;                          // after qkv
    ushort* ff1  = q_h;                           // 32 MiB over 16..48M (dead post-attn)

    dim3 blk256(256);
    prep<<<3328, blk256, 0, stream>>>(
        wq, wk, wv, wo, w1, w2, mask, x, g1, be1,
        wqkvt_h, wqt_l, wqkvt_h + 512 * 512,
        wqkvt_h + 1024 * 512, wot_h, w1t_h, w2t_h, mb, mflag, xn_h, xn_l);
    qkv_gemm<<<dim3(12, NROWS / 128), blk256, 0, stream>>>(
        xn_h, xn_l, wqkvt_h, wqt_l, bq, bk, bv, q_h, k_h, v_t);
    {
        dim3 grid(32, 16);  // 512 blocks: 32 bh x (2 parts x 8 qb of 256 rows)
        attn_kernel<<<grid, dim3(512), 0, stream>>>(
            q_h, k_h, v_t, mb, mflag, pctx0, pctx1, ml);
    }
    {
        dim3 grid(DM / 64, NROWS / 64);  // out-proj with fused combine
        mgemm64<false,true,0,true><<<grid, blk256, 0, stream>>>(
            nullptr, wot_h, bo, x, out, nullptr, pctx0, pctx1, ml,
            NROWS, DM, DM);
    }
    ln_kernel<false><<<NROWS / 4, blk256, 0, stream>>>(out, g2, be2, xn2, nullptr);
    {
        dim3 grid(DFF / 128, NROWS / 128);
        mgemm<true,false,1><<<grid, blk256, 0, stream>>>(
            xn2, w1t_h, b1, nullptr, nullptr, ff1, NROWS, DFF, DM);
    }
    {
        dim3 grid(DM / 64, NROWS / 64);
        mgemm64<false,true,0,false><<<grid, blk256, 0, stream>>>(
            ff1, w2t_h, b2, out, out, nullptr, nullptr, nullptr, nullptr,
            NROWS, DM, DFF);
    }
}